// Round 11
// baseline (284.203 us; speedup 1.0000x reference)
//
#include <hip/hip_runtime.h>
#include <math.h>

#define IN_F  256
#define OUT_F 256
#define OTILE 64      // o per block; lane = o
#define BTILE 8       // b per block; 2 per wave
#define NTH   256
#define NLAUNCH 11    // measurement round: slope of dur_us vs launch count gives true kernel cost

typedef _Float16 h2 __attribute__((ext_vector_type(2)));   // -> v_pk_* f16 ops

// out[b,o] = (1 + min_i((x-1)*pe)) * n0 + (-1 + max_i((x-1)*pe + 2*pe)) * n1
// pe = sigmoid(w0-w1); n0 = sigmoid(pw0-pw1); n1 = 1-n0.
// pe stored fp16 in 32KB swizzled LDS (4 blocks/CU); main math packed fp16.
__global__ __launch_bounds__(NTH, 4)
void den_kernel(const float* __restrict__ x,
                const float* __restrict__ pew,
                const float* __restrict__ pnw,
                float* __restrict__ out)
{
    __shared__ __align__(16) _Float16 pe_lds[OTILE * IN_F];   // 32 KB; row o at byte 512*o

    const int tid = threadIdx.x;
    const int b0  = blockIdx.x * BTILE;
    const int o0  = blockIdx.y * OTILE;

    // ---- stage pe = sigmoid -> fp16, swizzled: byte_in_row ^= (row&15)<<3 ----
    {
        const int r16 = tid >> 4;            // 0..15
        const int c   = tid & 15;            // 0..15 (16 consecutive float4 = 256B/16 lanes)
        for (int rg = 0; rg < 4; ++rg) {
            const int o  = rg * 16 + r16;    // 0..63
            const int sw = (o & 15) << 3;
            const float4* wp = reinterpret_cast<const float4*>(pew + (size_t)(o0 + o) * (IN_F * 2));
            char* rowp = reinterpret_cast<char*>(&pe_lds[o * IN_F]);
            #pragma unroll
            for (int k = 0; k < 8; ++k) {
                float4 w = wp[k * 16 + c];   // (w0_i, w1_i, w0_{i+1}, w1_{i+1})
                float pe0 = __builtin_amdgcn_rcpf(1.0f + __expf(w.y - w.x));
                float pe1 = __builtin_amdgcn_rcpf(1.0f + __expf(w.w - w.z));
                const int byteoff = (4 * (k * 16 + c)) ^ sw;   // 4B store stays 4B-aligned
                h2 pv; pv.x = (_Float16)pe0; pv.y = (_Float16)pe1;
                *reinterpret_cast<h2*>(rowp + byteoff) = pv;
            }
        }
    }
    __syncthreads();   // the only barrier

    const int lane = tid & 63;               // lane = o offset
    const int wid  = tid >> 6;               // 0..3
    const int bb0  = b0 + wid * 2;           // 2 b-rows per wave
    const char* rowp = reinterpret_cast<const char*>(&pe_lds[lane * IN_F]);
    const int sw = (lane & 15) << 3;

    const h2 two2 = {(_Float16)2.0f, (_Float16)2.0f};
    h2 mn[2], mx[2];
    #pragma unroll
    for (int j = 0; j < 2; ++j) {
        mn[j].x = mn[j].y = (_Float16)INFINITY;
        mx[j].x = mx[j].y = (_Float16)(-INFINITY);
    }

    const float* xr0 = x + (size_t)bb0 * IN_F;   // wave-uniform base

    // ---- main loop: 64 chunks of 4 i: 1 x 8B LDS read + per-j {16B x load, 10 pk ops} ----
    #pragma unroll 4
    for (int c = 0; c < 64; ++c) {
        h2 pA = *reinterpret_cast<const h2*>(rowp + ((8 * c) ^ sw));       // pe[i], pe[i+1]
        h2 pB = *reinterpret_cast<const h2*>(rowp + (((8 * c) ^ sw) + 4)); // pe[i+2], pe[i+3]
        #pragma unroll
        for (int j = 0; j < 2; ++j) {
            float4 xv = *reinterpret_cast<const float4*>(xr0 + j * IN_F + 4 * c);  // uniform addr
            h2 xA; xA.x = (_Float16)xv.x; xA.y = (_Float16)xv.y;
            h2 xB; xB.x = (_Float16)xv.z; xB.y = (_Float16)xv.w;
            h2 tA = __builtin_elementwise_fma(xA, pA, -pA);    // (x-1)*pe
            h2 tB = __builtin_elementwise_fma(xB, pB, -pB);
            h2 uA = __builtin_elementwise_fma(two2, pA, tA);   // t + 2*pe
            h2 uB = __builtin_elementwise_fma(two2, pB, tB);
            mn[j] = __builtin_elementwise_min(mn[j], __builtin_elementwise_min(tA, tB));
            mx[j] = __builtin_elementwise_max(mx[j], __builtin_elementwise_max(uA, uB));
        }
    }

    // ---- epilogue: node softmax + combine; coalesced b32 stores ----
    const int o = o0 + lane;
    float2 nw = *reinterpret_cast<const float2*>(pnw + 2 * (size_t)o);
    float n0 = __builtin_amdgcn_rcpf(1.0f + __expf(nw.y - nw.x));
    float n1 = 1.0f - n0;
    #pragma unroll
    for (int j = 0; j < 2; ++j) {
        float mnf = fminf((float)mn[j].x, (float)mn[j].y);
        float mxf = fmaxf((float)mx[j].x, (float)mx[j].y);
        out[(size_t)(bb0 + j) * OUT_F + o] = (mnf + 1.0f) * n0 + (mxf - 1.0f) * n1;
    }
}

extern "C" void kernel_launch(void* const* d_in, const int* in_sizes, int n_in,
                              void* d_out, int out_size, void* d_ws, size_t ws_size,
                              hipStream_t stream) {
    (void)d_ws; (void)ws_size; (void)n_in; (void)out_size;
    const float* x   = (const float*)d_in[0];
    const float* pew = (const float*)d_in[1];
    const float* pnw = (const float*)d_in[2];
    float* out = (float*)d_out;
    const int B = in_sizes[0] / IN_F;          // 2048
    dim3 grid(B / BTILE, OUT_F / OTILE);       // 256 x 4 = 1024 blocks (4/CU)
    // MEASUREMENT: 11 identical idempotent launches; slope vs Round-10's single
    // launch isolates true per-launch kernel cost from the harness floor.
    for (int rep = 0; rep < NLAUNCH; ++rep) {
        den_kernel<<<grid, NTH, 0, stream>>>(x, pew, pnw, out);
    }
}

// Round 12
// 71.159 us; speedup vs baseline: 3.9939x; 3.9939x over previous
//
#include <hip/hip_runtime.h>
#include <math.h>

#define IN_F  256
#define OUT_F 256
#define OTILE 64      // o per block; lane = o
#define BTILE 8       // b per block; 2 per wave
#define NTH   256

typedef _Float16 h2 __attribute__((ext_vector_type(2)));   // -> v_pk_* f16 ops
union u32h2 { unsigned int u; h2 h; };

// ---------------- prep: pe = sigmoid(w0-w1) -> fp16 table; x -> fp16 ----------------
// pe16: 256x256 fp16 = 128KB (uint = 2 values).  x16: 2048x256 fp16 = 1MB (uint2 = 4 values).
__global__ __launch_bounds__(256)
void prep_kernel(const float* __restrict__ x,
                 const float* __restrict__ pew,
                 unsigned int* __restrict__ pe16,
                 uint2* __restrict__ x16)
{
    const int bid = blockIdx.x;
    const int t   = threadIdx.x;
    if (bid < 128) {                       // pe: 32768 float4 of pew -> 32768 uints
        const int idx = bid * 256 + t;
        float4 w = reinterpret_cast<const float4*>(pew)[idx];   // (w0,w1) x2
        float pe0 = __builtin_amdgcn_rcpf(1.0f + __expf(w.y - w.x));
        float pe1 = __builtin_amdgcn_rcpf(1.0f + __expf(w.w - w.z));
        u32h2 r; r.h.x = (_Float16)pe0; r.h.y = (_Float16)pe1;
        pe16[idx] = r.u;
    } else {                               // x: 131072 float4 -> uint2 (4 fp16)
        const int idx = (bid - 128) * 256 + t;
        float4 v = reinterpret_cast<const float4*>(x)[idx];
        u32h2 a, b;
        a.h.x = (_Float16)v.x; a.h.y = (_Float16)v.y;
        b.h.x = (_Float16)v.z; b.h.y = (_Float16)v.w;
        x16[idx] = make_uint2(a.u, b.u);
    }
}

// ---------------- main: out[b,o] = (1+min_i t)*n0 + (max_i u - 1)*n1 ----------------
// t = (x-1)*pe = pk_fma(x, pe, -pe);  u = pk_fma(2, pe, t).  All pk fp16.
__global__ __launch_bounds__(NTH, 4)
void den_main(const unsigned int* __restrict__ pe16,
              const uint2* __restrict__ x16,
              const float* __restrict__ pnw,
              float* __restrict__ out)
{
    __shared__ __align__(16) unsigned int pe_lds[OTILE * (IN_F / 2)];  // 32KB; row o = 512B

    const int tid = threadIdx.x;
    const int b0  = blockIdx.x * BTILE;
    const int o0  = blockIdx.y * OTILE;

    // ---- stage pe tile (pure copies, swizzle byte^=(o&15)<<3 on 8B granules) ----
    {
        const int r16 = tid >> 4;          // 0..15
        const int c   = tid & 15;          // 0..15 -> 32B per lane per row
        #pragma unroll
        for (int rg = 0; rg < 4; ++rg) {
            const int o  = rg * 16 + r16;  // 0..63
            const int sw = (o & 15) << 3;
            const uint2* src = reinterpret_cast<const uint2*>(pe16 + (size_t)(o0 + o) * (IN_F / 2));
            char* rowp = reinterpret_cast<char*>(&pe_lds[o * (IN_F / 2)]);
            #pragma unroll
            for (int q = 0; q < 4; ++q) {
                uint2 v = src[c * 4 + q];                                  // 8B
                *reinterpret_cast<uint2*>(rowp + ((c * 32 + q * 8) ^ sw)) = v;
            }
        }
    }
    __syncthreads();   // the only barrier

    const int lane = tid & 63;                                  // lane = o offset
    const int wid  = __builtin_amdgcn_readfirstlane(tid >> 6);  // SGPR -> uniform x addrs
    const int bb0  = b0 + wid * 2;                              // 2 b-rows per wave
    const char* rowp = reinterpret_cast<const char*>(&pe_lds[lane * (IN_F / 2)]);
    const int sw = (lane & 15) << 3;

    const h2 two2 = {(_Float16)2.0f, (_Float16)2.0f};
    h2 mn[2], mx[2];
    #pragma unroll
    for (int j = 0; j < 2; ++j) {
        mn[j].x = mn[j].y = (_Float16)INFINITY;
        mx[j].x = mx[j].y = (_Float16)(-INFINITY);
    }

    const uint2* xr0 = x16 + (size_t)bb0 * (IN_F / 4);      // wave-uniform base (s_load path)
    const uint2* xr1 = x16 + (size_t)(bb0 + 1) * (IN_F / 4);

    // ---- main loop: 64 chunks of 4 i: 1 ds_read_b64 + 2 uniform 8B loads + 16 pk ops ----
    #pragma unroll 4
    for (int c = 0; c < 64; ++c) {
        uint2 pv = *reinterpret_cast<const uint2*>(rowp + ((8 * c) ^ sw));
        u32h2 pa, pb; pa.u = pv.x; pb.u = pv.y;       // pe[i..i+1], pe[i+2..i+3]
        const h2 pA = pa.h, pB = pb.h;

        uint2 xc0 = xr0[c];
        uint2 xc1 = xr1[c];
        u32h2 t0a, t0b, t1a, t1b;
        t0a.u = xc0.x; t0b.u = xc0.y; t1a.u = xc1.x; t1b.u = xc1.y;

        { // j = 0
            h2 tA = __builtin_elementwise_fma(t0a.h, pA, -pA);
            h2 tB = __builtin_elementwise_fma(t0b.h, pB, -pB);
            h2 uA = __builtin_elementwise_fma(two2, pA, tA);
            h2 uB = __builtin_elementwise_fma(two2, pB, tB);
            mn[0] = __builtin_elementwise_min(mn[0], __builtin_elementwise_min(tA, tB));
            mx[0] = __builtin_elementwise_max(mx[0], __builtin_elementwise_max(uA, uB));
        }
        { // j = 1
            h2 tA = __builtin_elementwise_fma(t1a.h, pA, -pA);
            h2 tB = __builtin_elementwise_fma(t1b.h, pB, -pB);
            h2 uA = __builtin_elementwise_fma(two2, pA, tA);
            h2 uB = __builtin_elementwise_fma(two2, pB, tB);
            mn[1] = __builtin_elementwise_min(mn[1], __builtin_elementwise_min(tA, tB));
            mx[1] = __builtin_elementwise_max(mx[1], __builtin_elementwise_max(uA, uB));
        }
    }

    // ---- epilogue: node softmax + combine; coalesced b32 stores ----
    const int o = o0 + lane;
    float2 nw = *reinterpret_cast<const float2*>(pnw + 2 * (size_t)o);
    float n0 = __builtin_amdgcn_rcpf(1.0f + __expf(nw.y - nw.x));
    float n1 = 1.0f - n0;
    #pragma unroll
    for (int j = 0; j < 2; ++j) {
        float mnf = fminf((float)mn[j].x, (float)mn[j].y);
        float mxf = fmaxf((float)mx[j].x, (float)mx[j].y);
        out[(size_t)(b0 + wid * 2 + j) * OUT_F + o] = (mnf + 1.0f) * n0 + (mxf - 1.0f) * n1;
    }
}

extern "C" void kernel_launch(void* const* d_in, const int* in_sizes, int n_in,
                              void* d_out, int out_size, void* d_ws, size_t ws_size,
                              hipStream_t stream) {
    (void)ws_size; (void)n_in; (void)out_size;
    const float* x   = (const float*)d_in[0];
    const float* pew = (const float*)d_in[1];
    const float* pnw = (const float*)d_in[2];
    float* out = (float*)d_out;

    unsigned int* pe16 = (unsigned int*)d_ws;                     // 128KB
    uint2*        x16  = (uint2*)((char*)d_ws + 131072);          // 1MB

    prep_kernel<<<640, 256, 0, stream>>>(x, pew, pe16, x16);

    const int B = in_sizes[0] / IN_F;          // 2048
    dim3 grid(B / BTILE, OUT_F / OTILE);       // 256 x 4 = 1024 blocks (4/CU)
    den_main<<<grid, NTH, 0, stream>>>(pe16, x16, pnw, out);
}

// Round 13
// 70.955 us; speedup vs baseline: 4.0054x; 1.0029x over previous
//
#include <hip/hip_runtime.h>
#include <math.h>

#define IN_F  256
#define OUT_F 256
#define OTILE 64      // o per block; lane = o
#define BTILE 8       // b per block; 2 per wave
#define NTH   256

typedef _Float16 h2 __attribute__((ext_vector_type(2)));   // -> v_pk_* f16 ops
union u32h2 { unsigned int u; h2 h; };

// ---------------- prep: pe = sigmoid(w0-w1) -> fp16 table; x -> fp16 ----------------
// pe16: 256x256 fp16 = 128KB (uint = 2 values).  x16: 2048x256 fp16 = 1MB (uint2 = 4 values).
__global__ __launch_bounds__(256)
void prep_kernel(const float* __restrict__ x,
                 const float* __restrict__ pew,
                 unsigned int* __restrict__ pe16,
                 uint2* __restrict__ x16)
{
    const int bid = blockIdx.x;
    const int t   = threadIdx.x;
    if (bid < 128) {                       // pe: 32768 float4 of pew -> 32768 uints
        const int idx = bid * 256 + t;
        float4 w = reinterpret_cast<const float4*>(pew)[idx];   // (w0,w1) x2
        float pe0 = __builtin_amdgcn_rcpf(1.0f + __expf(w.y - w.x));
        float pe1 = __builtin_amdgcn_rcpf(1.0f + __expf(w.w - w.z));
        u32h2 r; r.h.x = (_Float16)pe0; r.h.y = (_Float16)pe1;
        pe16[idx] = r.u;
    } else {                               // x: 131072 float4 -> uint2 (4 fp16)
        const int idx = (bid - 128) * 256 + t;
        float4 v = reinterpret_cast<const float4*>(x)[idx];
        u32h2 a, b;
        a.h.x = (_Float16)v.x; a.h.y = (_Float16)v.y;
        b.h.x = (_Float16)v.z; b.h.y = (_Float16)v.w;
        x16[idx] = make_uint2(a.u, b.u);
    }
}

// ---------------- main: out[b,o] = (1+min_i t)*n0 + (max_i u - 1)*n1 ----------------
// t = (x-1)*pe = pk_fma(x, pe, -pe);  u = pk_fma(2, pe, t).  All pk fp16.
// Inner loop is ALL-LDS (DS returns in-order -> counted lgkmcnt, deep pipelining;
// no SMEM s_load in the loop, which would force lgkmcnt(0) drains).
__global__ __launch_bounds__(NTH, 4)
void den_main(const unsigned int* __restrict__ pe16,
              const uint2* __restrict__ x16,
              const float* __restrict__ pnw,
              float* __restrict__ out)
{
    __shared__ __align__(16) unsigned int pe_lds[OTILE * (IN_F / 2)];  // 32KB; row o = 512B, swizzled
    __shared__ __align__(16) uint2        x_lds[BTILE * (IN_F / 4)];   // 4KB; row b = 64 uint2, linear

    const int tid = threadIdx.x;
    const int b0  = blockIdx.x * BTILE;
    const int o0  = blockIdx.y * OTILE;

    // ---- stage x tile: 8 rows x 64 uint2 (broadcast-read later; linear) ----
    {
        const int row = tid >> 5;          // 0..7
        const int idx = tid & 31;          // 0..31
        const uint2* src = x16 + (size_t)(b0 + row) * (IN_F / 4);
        x_lds[row * 64 + idx]      = src[idx];
        x_lds[row * 64 + idx + 32] = src[idx + 32];
    }

    // ---- stage pe tile (pure copies, swizzle byte^=(o&15)<<3 on 8B granules) ----
    {
        const int r16 = tid >> 4;          // 0..15
        const int c   = tid & 15;          // 0..15 -> 32B per lane per row
        #pragma unroll
        for (int rg = 0; rg < 4; ++rg) {
            const int o  = rg * 16 + r16;  // 0..63
            const int sw = (o & 15) << 3;
            const uint4* src4 = reinterpret_cast<const uint4*>(pe16 + (size_t)(o0 + o) * (IN_F / 2));
            char* rowp = reinterpret_cast<char*>(&pe_lds[o * (IN_F / 2)]);
            #pragma unroll
            for (int q = 0; q < 2; ++q) {
                uint4 v = src4[c * 2 + q];                       // 16B global load
                const int off = c * 32 + q * 16;
                *reinterpret_cast<uint2*>(rowp + ((off    ) ^ sw)) = make_uint2(v.x, v.y);
                *reinterpret_cast<uint2*>(rowp + ((off + 8) ^ sw)) = make_uint2(v.z, v.w);
            }
        }
    }
    __syncthreads();   // the only barrier

    const int lane = tid & 63;                                  // lane = o offset
    const int wid  = __builtin_amdgcn_readfirstlane(tid >> 6);  // 0..3
    const char* rowp = reinterpret_cast<const char*>(&pe_lds[lane * (IN_F / 2)]);
    const int sw = (lane & 15) << 3;
    const uint2* xw0 = &x_lds[(wid * 2 + 0) * 64];              // wave-uniform LDS addr -> broadcast
    const uint2* xw1 = &x_lds[(wid * 2 + 1) * 64];

    const h2 two2 = {(_Float16)2.0f, (_Float16)2.0f};
    h2 mn[2], mx[2];
    #pragma unroll
    for (int j = 0; j < 2; ++j) {
        mn[j].x = mn[j].y = (_Float16)INFINITY;
        mx[j].x = mx[j].y = (_Float16)(-INFINITY);
    }

    // ---- main loop: 64 chunks of 4 i: 3 ds_read_b64 + 16 pk ops, all-LDS ----
    #pragma unroll 8
    for (int c = 0; c < 64; ++c) {
        uint2 pv = *reinterpret_cast<const uint2*>(rowp + ((8 * c) ^ sw));
        uint2 xc0 = xw0[c];                 // broadcast (all lanes same addr)
        uint2 xc1 = xw1[c];
        u32h2 pa, pb; pa.u = pv.x; pb.u = pv.y;
        const h2 pA = pa.h, pB = pb.h;
        u32h2 t0a, t0b, t1a, t1b;
        t0a.u = xc0.x; t0b.u = xc0.y; t1a.u = xc1.x; t1b.u = xc1.y;

        { // j = 0
            h2 tA = __builtin_elementwise_fma(t0a.h, pA, -pA);
            h2 tB = __builtin_elementwise_fma(t0b.h, pB, -pB);
            h2 uA = __builtin_elementwise_fma(two2, pA, tA);
            h2 uB = __builtin_elementwise_fma(two2, pB, tB);
            mn[0] = __builtin_elementwise_min(mn[0], __builtin_elementwise_min(tA, tB));
            mx[0] = __builtin_elementwise_max(mx[0], __builtin_elementwise_max(uA, uB));
        }
        { // j = 1
            h2 tA = __builtin_elementwise_fma(t1a.h, pA, -pA);
            h2 tB = __builtin_elementwise_fma(t1b.h, pB, -pB);
            h2 uA = __builtin_elementwise_fma(two2, pA, tA);
            h2 uB = __builtin_elementwise_fma(two2, pB, tB);
            mn[1] = __builtin_elementwise_min(mn[1], __builtin_elementwise_min(tA, tB));
            mx[1] = __builtin_elementwise_max(mx[1], __builtin_elementwise_max(uA, uB));
        }
    }

    // ---- epilogue: node softmax + combine; coalesced b32 stores ----
    const int o = o0 + lane;
    float2 nw = *reinterpret_cast<const float2*>(pnw + 2 * (size_t)o);
    float n0 = __builtin_amdgcn_rcpf(1.0f + __expf(nw.y - nw.x));
    float n1 = 1.0f - n0;
    #pragma unroll
    for (int j = 0; j < 2; ++j) {
        float mnf = fminf((float)mn[j].x, (float)mn[j].y);
        float mxf = fmaxf((float)mx[j].x, (float)mx[j].y);
        out[(size_t)(b0 + wid * 2 + j) * OUT_F + o] = (mnf + 1.0f) * n0 + (mxf - 1.0f) * n1;
    }
}

extern "C" void kernel_launch(void* const* d_in, const int* in_sizes, int n_in,
                              void* d_out, int out_size, void* d_ws, size_t ws_size,
                              hipStream_t stream) {
    (void)ws_size; (void)n_in; (void)out_size;
    const float* x   = (const float*)d_in[0];
    const float* pew = (const float*)d_in[1];
    const float* pnw = (const float*)d_in[2];
    float* out = (float*)d_out;

    unsigned int* pe16 = (unsigned int*)d_ws;                     // 128KB
    uint2*        x16  = (uint2*)((char*)d_ws + 131072);          // 1MB

    prep_kernel<<<640, 256, 0, stream>>>(x, pew, pe16, x16);

    const int B = in_sizes[0] / IN_F;          // 2048
    dim3 grid(B / BTILE, OUT_F / OTILE);       // 256 x 4 = 1024 blocks (4/CU)
    den_main<<<grid, NTH, 0, stream>>>(pe16, x16, pnw, out);
}